// Round 4
// baseline (23464.326 us; speedup 1.0000x reference)
//
#include <hip/hip_runtime.h>
#include <hip/hip_bf16.h>

#define B_   1024
#define L_   50
#define E_   128
#define H_   128
#define G_   384      // 3*H
#define NI_  100000

typedef float f32x4 __attribute__((ext_vector_type(4)));

// ---------------------------------------------------------------- lengths
__global__ void k_len(const int* __restrict__ items, int* __restrict__ len) {
    int b = blockIdx.x * 256 + threadIdx.x;
    if (b >= B_) return;
    int c = 0;
    #pragma unroll
    for (int l = 0; l < L_; ++l) c += (items[b * L_ + l] != 0);
    len[b] = c > 0 ? c : 1;
}

// ------------------------------------------------- gates_x = gather+GEMM
__global__ __launch_bounds__(384) void k_gates(const int* __restrict__ items,
                                               const float* __restrict__ emb,
                                               const float* __restrict__ Wih,
                                               const float* __restrict__ bih,
                                               float* __restrict__ gx) {
    __shared__ float4 xs[32][32];            // [row][kquad], broadcast reads
    const int m0 = blockIdx.x * 32;
    const int tid = threadIdx.x;
    for (int i = tid; i < 32 * 32; i += 384) {
        int r = i >> 5, kq = i & 31;
        int it = items[m0 + r];
        xs[r][kq] = ((const float4*)emb)[(size_t)it * 32 + kq];
    }
    __syncthreads();
    const int g = tid;                       // 0..383
    float acc[32];
    #pragma unroll
    for (int r = 0; r < 32; ++r) acc[r] = 0.0f;
    const float4* W4 = (const float4*)Wih;
    #pragma unroll
    for (int kq = 0; kq < 32; ++kq) {
        float4 w = W4[g * 32 + kq];
        #pragma unroll
        for (int r = 0; r < 32; ++r) {
            float4 x = xs[r][kq];
            acc[r] += x.x * w.x + x.y * w.y + x.z * w.z + x.w * w.w;
        }
    }
    const float bb = bih[g];
    #pragma unroll
    for (int r = 0; r < 32; ++r)
        gx[(size_t)(m0 + r) * G_ + g] = acc[r] + bb;
}

// ------------------------------------------------------- GRU recurrence
__global__ __launch_bounds__(384, 1) void k_gru(const float* __restrict__ gx,
                                                const float* __restrict__ Whh,
                                                const float* __restrict__ bhh,
                                                const int* __restrict__ len,
                                                float* __restrict__ last) {
    __shared__ float4 hs[4][32];             // h state, [row][kquad]
    __shared__ float  ghs[4][G_];            // gh scratch per step
    __shared__ int    lens[4];
    const int b0 = blockIdx.x * 4;
    const int g  = threadIdx.x;

    float4 w[32];
    const float4* W4 = (const float4*)Whh;
    #pragma unroll
    for (int kq = 0; kq < 32; ++kq) w[kq] = W4[g * 32 + kq];
    const float bg = bhh[g];

    if (g < 4) lens[g] = len[b0 + g];
    for (int i = g; i < 4 * 32; i += 384) hs[i >> 5][i & 31] = make_float4(0.f, 0.f, 0.f, 0.f);
    __syncthreads();

    for (int t = 0; t < L_; ++t) {
        float a0 = bg, a1 = bg, a2 = bg, a3 = bg;
        #pragma unroll
        for (int kq = 0; kq < 32; ++kq) {
            float4 wv = w[kq];
            float4 h0 = hs[0][kq], h1 = hs[1][kq], h2 = hs[2][kq], h3 = hs[3][kq];
            a0 += h0.x * wv.x + h0.y * wv.y + h0.z * wv.z + h0.w * wv.w;
            a1 += h1.x * wv.x + h1.y * wv.y + h1.z * wv.z + h1.w * wv.w;
            a2 += h2.x * wv.x + h2.y * wv.y + h2.z * wv.z + h2.w * wv.w;
            a3 += h3.x * wv.x + h3.y * wv.y + h3.z * wv.z + h3.w * wv.w;
        }
        ghs[0][g] = a0; ghs[1][g] = a1; ghs[2][g] = a2; ghs[3][g] = a3;
        __syncthreads();
        for (int i = g; i < 4 * 128; i += 384) {
            int r = i >> 7, j = i & 127;
            size_t base = ((size_t)(b0 + r) * L_ + t) * G_;
            float xr = gx[base + j], xz = gx[base + 128 + j], xn = gx[base + 256 + j];
            float hr = ghs[r][j],    hz = ghs[r][128 + j],    hn = ghs[r][256 + j];
            float rg = 1.0f / (1.0f + expf(-(xr + hr)));
            float z  = 1.0f / (1.0f + expf(-(xz + hz)));
            float nn = tanhf(xn + rg * hn);
            float hp = ((const float*)hs[r])[j];
            float hv = (1.0f - z) * nn + z * hp;
            ((float*)hs[r])[j] = hv;
            if (t == lens[r] - 1) last[(size_t)(b0 + r) * H_ + j] = hv;
        }
        __syncthreads();
    }
}

// ----------------------------------------------------------- cls = last @ Wproj^T
__global__ __launch_bounds__(128) void k_cls(const float* __restrict__ last,
                                             const float* __restrict__ Wp,
                                             float* __restrict__ cls) {
    __shared__ float4 hl[32];
    const int b = blockIdx.x, e = threadIdx.x;
    if (e < 32) hl[e] = ((const float4*)last)[b * 32 + e];
    __syncthreads();
    float acc = 0.0f;
    const float4* W4 = (const float4*)Wp;
    #pragma unroll
    for (int kq = 0; kq < 32; ++kq) {
        float4 w = W4[e * 32 + kq];
        float4 h = hl[kq];
        acc += h.x * w.x + h.y * w.y + h.z * w.z + h.w * w.w;
    }
    cls[(size_t)b * E_ + e] = acc;
}

// ----------------------------------------------------- scores = cls @ emb^T + bias
// v3: BM=64 x BN=128, BK=32 quarters, double-buffered global_load_lds(16B)
// with counted vmcnt(6) (never drained in-loop), raw s_barriers.
// LDS 48 KB -> 3 blocks/CU. XOR swizzle applied on the GLOBAL source address
// (global_load_lds writes linearly) and matched on the LDS read side:
//   A slot (row,c) holds global col c ^ ((row>>2)&7)  -> read col kq^(ty&7): conflict-free
//   B slot (row,c) holds global col c ^ ((row>>3)&7)  -> read col kq^((nl>>3)&7): 2-way (free)
// XCD-bijective block swizzle: 12512 blocks = 8 * 1564; XCD x owns n-stripe
// chunk, m-tiles inner -> each emb slice fills exactly one L2; cls L2-resident.
// Output written with nontemporal float4 stores (pure 410 MB stream, no reuse).
__device__ __forceinline__ void stage_tiles(int q, f32x4 (*Asb)[8], f32x4 (*Bsb)[8],
                                            int wave, int lane, int m0, int n0,
                                            const f32x4* cls4, const f32x4* emb4) {
    const int rsub = lane >> 3;      // 0..7
    const int c    = lane & 7;       // 0..7
    #pragma unroll
    for (int k = 0; k < 2; ++k) {    // A: 8 rows per instr, 2 instrs/wave
        int a   = wave * 2 + k;
        int row = a * 8 + rsub;
        int col = q * 8 + (c ^ ((row >> 2) & 7));
        __builtin_amdgcn_global_load_lds(
            (const __attribute__((address_space(1))) void*)(cls4 + (size_t)(m0 + row) * 32 + col),
            (__attribute__((address_space(3))) void*)&Asb[a * 8][0], 16, 0, 0);
    }
    #pragma unroll
    for (int k = 0; k < 4; ++k) {    // B: 8 rows per instr, 4 instrs/wave
        int b   = wave * 4 + k;
        int row = b * 8 + rsub;
        int n   = n0 + row;
        n = (n < NI_) ? n : (NI_ - 1);          // clamp: avoid OOB read on last tile
        int col = q * 8 + (c ^ ((row >> 3) & 7));
        __builtin_amdgcn_global_load_lds(
            (const __attribute__((address_space(1))) void*)(emb4 + (size_t)n * 32 + col),
            (__attribute__((address_space(3))) void*)&Bsb[b * 8][0], 16, 0, 0);
    }
}

__global__ __launch_bounds__(256, 3) void k_scores(const float* __restrict__ cls,
                                                   const float* __restrict__ emb,
                                                   const float* __restrict__ bias,
                                                   float* __restrict__ out) {
    __shared__ f32x4 As[2][64][8];           // 16 KB
    __shared__ f32x4 Bs[2][128][8];          // 32 KB
    const int orig = blockIdx.x;             // 0..12511 = 8*1564
    const int lid  = (orig & 7) * 1564 + (orig >> 3);
    const int m0 = (lid & 15) * 64;          // m-tiles inner within XCD chunk
    const int n0 = (lid >> 4) * 128;
    const int tid  = threadIdx.x;
    const int wave = tid >> 6, lane = tid & 63;
    const int tx = tid & 15, ty = tid >> 4;
    const f32x4* cls4 = (const f32x4*)cls;
    const f32x4* emb4 = (const f32x4*)emb;

    float acc[4][2][4] = {};

    stage_tiles(0, As[0], Bs[0], wave, lane, m0, n0, cls4, emb4);

    #pragma unroll
    for (int q = 0; q < 4; ++q) {
        const int buf = q & 1;
        if (q < 3)
            stage_tiles(q + 1, As[buf ^ 1], Bs[buf ^ 1], wave, lane, m0, n0, cls4, emb4);
        if (q < 3) asm volatile("s_waitcnt vmcnt(6)" ::: "memory");
        else       asm volatile("s_waitcnt vmcnt(0)" ::: "memory");
        __builtin_amdgcn_s_barrier();        // all waves staged buf q

        #pragma unroll
        for (int kq = 0; kq < 8; ++kq) {
            f32x4 aq[4], bq[2][4];
            #pragma unroll
            for (int i = 0; i < 4; ++i)
                aq[i] = As[buf][ty * 4 + i][kq ^ (ty & 7)];
            #pragma unroll
            for (int j4 = 0; j4 < 2; ++j4)
                #pragma unroll
                for (int j = 0; j < 4; ++j) {
                    int nl = j4 * 64 + tx * 4 + j;
                    bq[j4][j] = Bs[buf][nl][kq ^ ((nl >> 3) & 7)];
                }
            #pragma unroll
            for (int i = 0; i < 4; ++i)
                #pragma unroll
                for (int j4 = 0; j4 < 2; ++j4)
                    #pragma unroll
                    for (int j = 0; j < 4; ++j)
                        acc[i][j4][j] += aq[i][0] * bq[j4][j][0] + aq[i][1] * bq[j4][j][1]
                                       + aq[i][2] * bq[j4][j][2] + aq[i][3] * bq[j4][j][3];
        }
        __builtin_amdgcn_s_barrier();        // all waves done reading buf q
    }

    const f32x4* bias4 = (const f32x4*)bias;
    #pragma unroll
    for (int j4 = 0; j4 < 2; ++j4) {
        const int n = n0 + j4 * 64 + tx * 4;
        if (n < NI_) {                       // n%4==0, so n<NI_ implies n+3<NI_
            f32x4 bv = bias4[n >> 2];
            #pragma unroll
            for (int i = 0; i < 4; ++i) {
                const int m = m0 + ty * 4 + i;
                f32x4 o;
                o[0] = acc[i][j4][0] + bv[0];
                o[1] = acc[i][j4][1] + bv[1];
                o[2] = acc[i][j4][2] + bv[2];
                o[3] = acc[i][j4][3] + bv[3];
                __builtin_nontemporal_store(o, (f32x4*)(out + (size_t)m * NI_ + n));
            }
        }
    }
}

// ---------------------------------------------------------------- launch
extern "C" void kernel_launch(void* const* d_in, const int* in_sizes, int n_in,
                              void* d_out, int out_size, void* d_ws, size_t ws_size,
                              hipStream_t stream) {
    const int*   items = (const int*)  d_in[0];
    const float* emb   = (const float*)d_in[1];
    const float* Wih   = (const float*)d_in[2];
    const float* Whh   = (const float*)d_in[3];
    const float* bih   = (const float*)d_in[4];
    const float* bhh   = (const float*)d_in[5];
    const float* Wp    = (const float*)d_in[6];
    const float* bias  = (const float*)d_in[7];
    float* out = (float*)d_out;

    char* ws = (char*)d_ws;
    float* gx   = (float*)(ws);                                   // 78,643,200 B
    int*   len  = (int*)  (ws + 78643200);                        //      4,096 B
    float* last = (float*)(ws + 78643200 + 4096);                 //    524,288 B
    float* cls  = (float*)(ws + 78643200 + 4096 + 524288);        //    524,288 B

    k_len   <<<dim3((B_ + 255) / 256), dim3(256), 0, stream>>>(items, len);
    k_gates <<<dim3((B_ * L_) / 32),   dim3(384), 0, stream>>>(items, emb, Wih, bih, gx);
    k_gru   <<<dim3(B_ / 4),           dim3(384), 0, stream>>>(gx, Whh, bhh, len, last);
    k_cls   <<<dim3(B_),               dim3(128), 0, stream>>>(last, Wp, cls);
    // 16 m-tiles x 782 n-tiles = 12512 blocks (= 8 * 1564, bijective XCD swizzle)
    k_scores<<<dim3(12512), dim3(256), 0, stream>>>(cls, emb, bias, out);
}